// Round 6
// baseline (403.975 us; speedup 1.0000x reference)
//
#include <hip/hip_runtime.h>
#include <hip/hip_bf16.h>
#include <cmath>

// PREFFFT: masked-spectrum iFFT2 (3 planes x 128ch x 256x256) + bilinear
// grid-sample at 262144 points + 8-term Fourier integration -> (N,16).
//
// R6: pass epilogues were store-issue-bound (pass2: 8x 2B scalar stores per
// thread = 50M store insts ~ 80us). Both passes now emit one/two uint4
// stores per thread (full 64B lines per wave). Gather atomicAdds into
// d_out directly (partial+combine removed; d_out memset to 0 first).
// Sort kernels fused across planes (one pts read). Gather keeps R5's
// XCD-chunk swizzle (FETCH 59MB, L2-resident).

#define NPTS 262144

typedef float vf2 __attribute__((ext_vector_type(2)));

__device__ __forceinline__ int brev8(int x) { return (int)(__brev((unsigned)x) >> 24); }

__device__ __forceinline__ unsigned pack_bf16(float2 v) {
    unsigned short a = __builtin_bit_cast(unsigned short, __float2bfloat16(v.x));
    unsigned short b = __builtin_bit_cast(unsigned short, __float2bfloat16(v.y));
    return (unsigned)a | ((unsigned)b << 16);
}
__device__ __forceinline__ float2 unpack_bf16(unsigned u) {
    return make_float2(__uint_as_float(u << 16), __uint_as_float(u & 0xffff0000u));
}
__device__ __forceinline__ vf2 up2(unsigned u) {
    vf2 r; r.x = __uint_as_float(u << 16); r.y = __uint_as_float(u & 0xffff0000u);
    return r;
}

// plane coordinate mapping (matches reference):
// p=0: gx=in1 gy=in2 s=in0 | p=1: gx=in0 gy=in2 s=in1 | p=2: gx=in0 gy=in1 s=in2
__device__ __forceinline__ void plane_coords(int p, float in0, float in1, float in2,
                                             float& gx, float& gy, float& sc) {
    gx = (p == 0) ? in1 : in0;
    gy = (p == 2) ? in1 : in2;
    sc = (p == 0) ? in0 : ((p == 1) ? in1 : in2);
}

// ---------------- Pass 1: iFFT over y for each (plane, ch, x<128) column ---
// Cooperative load/store; butterfly stages wave-private (wave w: cols 2w,2w+1).
__global__ __launch_bounds__(512) void pass1_kernel(const float* __restrict__ P0,
                                                    const float* __restrict__ P1,
                                                    const float* __restrict__ P2,
                                                    unsigned* __restrict__ X) {
    __shared__ float2 tw[128];
    __shared__ float2 tile[256 * 17];

    int t = threadIdx.x;
    if (t < 128) {
        float s, c;
        sincospif((float)t * (1.0f / 128.0f), &s, &c);
        tw[t] = make_float2(c, s);
    }
    int plane = blockIdx.y;
    const float* P = (plane == 0) ? P0 : ((plane == 1) ? P1 : P2);
    unsigned* Xp = X + (size_t)plane * 4194304;

    int b  = blockIdx.x;
    int ch = b >> 3;
    int x0 = (b & 7) << 4;
    const float* src = P + (size_t)ch * 131072 + x0 * 2;

    const float scale = 1.0f / 65536.0f;
#pragma unroll
    for (int k = 0; k < 2; k++) {
        int i = t + (k << 9);
        int y = i >> 3;
        int j = i & 7;
        float4 v = *(const float4*)(src + (size_t)y * 512 + (j << 2));
        float2 c0 = make_float2(v.x * scale, v.y * scale);
        float2 c1 = make_float2(v.z * scale, v.w * scale);
        int pos = brev8(y);             // even; writing pos and pos+1 folds stage 1
        tile[pos * 17 + 2 * j]           = c0;
        tile[(pos + 1) * 17 + 2 * j]     = c0;
        tile[pos * 17 + 2 * j + 1]       = c1;
        tile[(pos + 1) * 17 + 2 * j + 1] = c1;
    }
    __syncthreads();

    int w = t >> 6, l = t & 63;
    int col = (w << 1) + (l & 1);       // wave-private column
    int bb  = l >> 1;                   // 0..31
#pragma unroll
    for (int s = 2; s <= 8; s++) {
        int half = 1 << (s - 1);
#pragma unroll
        for (int k = 0; k < 4; k++) {
            int bf = bb + (k << 5);     // 0..127
            int j  = bf & (half - 1);
            int g  = bf >> (s - 1);
            int i0 = (g << s) + j;
            int i1 = i0 + half;
            float2 u = tile[i0 * 17 + col];
            float2 v = tile[i1 * 17 + col];
            float2 wq = tw[j << (8 - s)];
            float2 vt = make_float2(v.x * wq.x - v.y * wq.y, v.x * wq.y + v.y * wq.x);
            tile[i0 * 17 + col] = make_float2(u.x + vt.x, u.y + vt.y);
            tile[i1 * 17 + col] = make_float2(u.x - vt.x, u.y - vt.y);
        }
    }
    __syncthreads();

    // vectorized epilogue: thread owns (v, 4 consecutive c) -> uint4 store.
    unsigned* dst = Xp + (size_t)ch * 32768 + x0;
    int c4 = (t & 3) << 2;              // 0,4,8,12
    int v0 = t >> 2;                    // 0..127
#pragma unroll
    for (int k = 0; k < 2; k++) {
        int v = v0 + (k << 7);
        const float2* tp = &tile[v * 17 + c4];
        uint4 o;
        o.x = pack_bf16(tp[0]);
        o.y = pack_bf16(tp[1]);
        o.z = pack_bf16(tp[2]);
        o.w = pack_bf16(tp[3]);
        *(uint4*)(dst + (size_t)v * 128 + c4) = o;
    }
}

// ---------------- Pass 2: iFFT over x, store feat as bf16 -------------------
// Rows are wave-private: no per-stage barriers. Epilogue: 1 uint4 store/thread.
__global__ __launch_bounds__(1024) void pass2_kernel(const unsigned* __restrict__ X,
                                                     __hip_bfloat16* __restrict__ feat) {
    __shared__ float2 tw[128];
    __shared__ float2 rows[16 * 257];

    int t = threadIdx.x;
    if (t < 128) {
        float s, c;
        sincospif((float)t * (1.0f / 128.0f), &s, &c);
        tw[t] = make_float2(c, s);
    }
    int w = t >> 6;
    int l = t & 63;
    int v   = blockIdx.x & 255;
    int g   = blockIdx.x >> 8;
    int ch0 = g << 4;
    int ch  = ch0 + w;
    int plane = blockIdx.y;
    const unsigned* Xp = X + (size_t)plane * 4194304;
    __hip_bfloat16* fp = feat + (size_t)plane * 16777216;

    const uint2* src = (const uint2*)(Xp + ((size_t)ch * 256 + v) * 128);
    uint2 d = src[l];
    float2 c0 = unpack_bf16(d.x);
    float2 c1 = unpack_bf16(d.y);
    float2* row = rows + w * 257;
    int p0 = brev8(2 * l);
    int p1 = brev8(2 * l + 1);
    row[p0]     = c0;
    row[p0 + 1] = c0;
    row[p1]     = c1;
    row[p1 + 1] = c1;
    __syncthreads();                    // covers tw init (rows are wave-private)
#pragma unroll
    for (int s = 2; s <= 8; s++) {
        int half = 1 << (s - 1);
#pragma unroll
        for (int k = 0; k < 2; k++) {
            int bf = l + (k << 6);
            int j  = bf & (half - 1);
            int gg = bf >> (s - 1);
            int i0 = (gg << s) + j;
            int i1 = i0 + half;
            float2 u  = row[i0];
            float2 vv = row[i1];
            float2 wq = tw[j << (8 - s)];
            float2 vt = make_float2(vv.x * wq.x - vv.y * wq.y,
                                    vv.x * wq.y + vv.y * wq.x);
            row[i0] = make_float2(u.x + vt.x, u.y + vt.y);
            row[i1] = make_float2(u.x - vt.x, u.y - vt.y);
        }
    }
    __syncthreads();                    // epilogue reads other waves' rows

    // thread owns (x, 8 consecutive j = 4 channels re/im) -> one uint4 store.
    __hip_bfloat16* dst = fp + (size_t)v * 65536 + (ch0 << 1);
    int j8  = (t & 3) << 3;             // 0,8,16,24
    int x   = t >> 2;                   // 0..255
    int jj0 = j8 >> 1;                  // 0,4,8,12 channel-in-group
    uint4 o;
    o.x = pack_bf16(rows[(jj0 + 0) * 257 + x]);
    o.y = pack_bf16(rows[(jj0 + 1) * 257 + x]);
    o.z = pack_bf16(rows[(jj0 + 2) * 257 + x]);
    o.w = pack_bf16(rows[(jj0 + 3) * 257 + x]);
    *(uint4*)(dst + x * 256 + j8) = o;
}

// ---------------- Sort: histogram / scan / scatter (all planes fused) -------
__device__ __forceinline__ int tile_key(float gx, float gy) {
    float xf = (gx + 1.0f) * 127.5f;
    float yf = (gy + 1.0f) * 127.5f;
    int x0 = max(0, min((int)floorf(xf), 255));
    int y0 = max(0, min((int)floorf(yf), 255));
    return (y0 & 0xF0) | (x0 >> 4);
}

__global__ __launch_bounds__(1024) void hist_kernel(const float* __restrict__ pts,
                                                    unsigned* __restrict__ hist) {
    __shared__ unsigned hb[768];
    int t = threadIdx.x;
    int n = (blockIdx.x << 10) + t;
    if (t < 768) hb[t] = 0;
    __syncthreads();
    float in0 = pts[3 * n + 0], in1 = pts[3 * n + 1], in2 = pts[3 * n + 2];
#pragma unroll
    for (int p = 0; p < 3; p++) {
        float gx, gy, sc;
        plane_coords(p, in0, in1, in2, gx, gy, sc);
        atomicAdd(&hb[(p << 8) + tile_key(gx, gy)], 1u);
    }
    __syncthreads();
    if (t < 768 && hb[t]) atomicAdd(&hist[t], hb[t]);
}

__global__ __launch_bounds__(256) void scan_kernel(const unsigned* __restrict__ hist,
                                                   unsigned* __restrict__ cursor) {
    __shared__ unsigned s[256];
    int t = threadIdx.x;
    for (int p = 0; p < 3; p++) {
        unsigned v = hist[(p << 8) + t];
        s[t] = v;
        __syncthreads();
#pragma unroll
        for (int d = 1; d < 256; d <<= 1) {
            unsigned add = (t >= d) ? s[t - d] : 0u;
            __syncthreads();
            s[t] += add;
            __syncthreads();
        }
        cursor[(p << 8) + t] = s[t] - v;   // exclusive prefix
        __syncthreads();
    }
}

// writes per-plane sorted point table: (gx, gy, s, bitcast(n))
__global__ __launch_bounds__(1024) void scatter_kernel(const float* __restrict__ pts,
                                                       unsigned* __restrict__ cursor,
                                                       float4* __restrict__ psort) {
    __shared__ unsigned cnt[768];
    __shared__ unsigned base[768];
    int t = threadIdx.x;
    int n = (blockIdx.x << 10) + t;
    if (t < 768) cnt[t] = 0;
    __syncthreads();
    float in0 = pts[3 * n + 0], in1 = pts[3 * n + 1], in2 = pts[3 * n + 2];
    float gxs[3], gys[3], scs[3];
    int key[3];
    unsigned rank[3];
#pragma unroll
    for (int p = 0; p < 3; p++) {
        plane_coords(p, in0, in1, in2, gxs[p], gys[p], scs[p]);
        key[p] = (p << 8) + tile_key(gxs[p], gys[p]);
        rank[p] = atomicAdd(&cnt[key[p]], 1u);
    }
    __syncthreads();
    if (t < 768 && cnt[t]) base[t] = atomicAdd(&cursor[t], cnt[t]);
    __syncthreads();
#pragma unroll
    for (int p = 0; p < 3; p++) {
        psort[p * NPTS + base[key[p]] + rank[p]] =
            make_float4(gxs[p], gys[p], scs[p], __int_as_float(n));
    }
}

// ---------------- Gather (sorted, XCD-chunk swizzled, atomic output) --------
__global__ __launch_bounds__(256) void gather_kernel(const ushort* __restrict__ feat,
                                                     const float4* __restrict__ psort,
                                                     float* __restrict__ out) {
    int t = threadIdx.x;
    int w = t >> 6;
    int l = t & 63;
    int h = l >> 5;                     // point within wave
    int q = l & 31;                     // owns m = 8q..8q+7
    int p = blockIdx.y;
    const ushort* fb = feat + (size_t)p * 16777216;

    // XCD swizzle: dispatch b -> XCD b%8; give each XCD one contiguous chunk
    int b  = blockIdx.x;                        // 0..32767
    int lb = ((b & 7) << 12) | (b >> 3);        // logical sorted block
    int idx = (lb << 3) + (w << 1) + h;
    float4 pt = psort[p * NPTS + idx];
    float gx = pt.x, gy = pt.y, sc = pt.z;
    int n = __float_as_int(pt.w);

    float xf = (gx + 1.0f) * 127.5f;
    float yf = (gy + 1.0f) * 127.5f;
    float x0f = floorf(xf);
    float y0f = floorf(yf);
    float wx = xf - x0f;
    float wy = yf - y0f;
    int x0 = max(0, min((int)x0f, 255));
    int y0 = max(0, min((int)y0f, 255));
    int dx = (x0 < 255) ? 256 : 0;      // +1 pixel in x = 256 ushorts
    int dy = (y0 < 255) ? 65536 : 0;    // +1 pixel in y = 65536 ushorts

    const ushort* bp = fb + (((y0 << 8) + x0) << 8) + (q << 3);
    uint4 d00 = *(const uint4*)bp;
    uint4 d01 = *(const uint4*)(bp + dx);
    uint4 d10 = *(const uint4*)(bp + dy);
    uint4 d11 = *(const uint4*)(bp + dx + dy);

    // weights: lane with r=q&7 computes theta_r; broadcast merged cos/-sin
    float coef = (float)((1 << (q & 7)) - 1);
    float a = (sc + 1.0f) * 0.99609375f * coef;   // theta/pi
    float sn, cs;
    sincospif(a, &sn, &cs);
    float merged = (q < 16) ? cs : -sn;
    float wr0 = __shfl(merged, (l & 48) + 0);
    float wr1 = __shfl(merged, (l & 48) + 1);
    float wr2 = __shfl(merged, (l & 48) + 2);
    float wr3 = __shfl(merged, (l & 48) + 3);
    float wr4 = __shfl(merged, (l & 48) + 4);
    float wr5 = __shfl(merged, (l & 48) + 5);
    float wr6 = __shfl(merged, (l & 48) + 6);
    float wr7 = __shfl(merged, (l & 48) + 7);

    float w00 = (1.0f - wx) * (1.0f - wy);
    float w01 = wx * (1.0f - wy);
    float w10 = (1.0f - wx) * wy;
    float w11 = wx * wy;

    // packed-fp32 bilerp then dot with the broadcast weights
    vf2 b0 = w00 * up2(d00.x) + w01 * up2(d01.x) + w10 * up2(d10.x) + w11 * up2(d11.x);
    vf2 b1 = w00 * up2(d00.y) + w01 * up2(d01.y) + w10 * up2(d10.y) + w11 * up2(d11.y);
    vf2 b2 = w00 * up2(d00.z) + w01 * up2(d01.z) + w10 * up2(d10.z) + w11 * up2(d11.z);
    vf2 b3 = w00 * up2(d00.w) + w01 * up2(d01.w) + w10 * up2(d10.w) + w11 * up2(d11.w);

    vf2 wa; wa.x = wr0; wa.y = wr1;
    vf2 wb; wb.x = wr2; wb.y = wr3;
    vf2 wc; wc.x = wr4; wc.y = wr5;
    vf2 wd; wd.x = wr6; wd.y = wr7;
    vf2 acc2 = b0 * wa + b1 * wb + b2 * wc + b3 * wd;
    float acc = acc2.x + acc2.y;

    acc += __shfl_xor(acc, 16);         // cos-lane c + sin-lane c+16
    if (q < 16) {
        atomicAdd(&out[((size_t)n << 4) + q], acc);
    }
}

extern "C" void kernel_launch(void* const* d_in, const int* in_sizes, int n_in,
                              void* d_out, int out_size, void* d_ws, size_t ws_size,
                              hipStream_t stream) {
    const float* P0  = (const float*)d_in[0];
    const float* P1  = (const float*)d_in[1];
    const float* P2  = (const float*)d_in[2];
    const float* pts = (const float*)d_in[3];
    float* out = (float*)d_out;
    char* ws = (char*)d_ws;

    // ws layout (bytes):
    __hip_bfloat16* feat = (__hip_bfloat16*)ws;                    // 100,663,296
    unsigned* X          = (unsigned*)(ws + 100663296u);           //  50,331,648
    float4*   psort      = (float4*)(ws + 150994944u);             //  12,582,912
    unsigned* hist       = (unsigned*)(ws + 163577856u);           //       3,072
    unsigned* cursor     = (unsigned*)(ws + 163580928u);           //       3,072

    hipMemsetAsync(hist, 0, 3072, stream);
    hipMemsetAsync(out, 0, (size_t)out_size * sizeof(float), stream);

    dim3 g1(1024, 3);
    pass1_kernel<<<g1, 512, 0, stream>>>(P0, P1, P2, X);
    dim3 g2(2048, 3);
    pass2_kernel<<<g2, 1024, 0, stream>>>(X, feat);

    hist_kernel<<<256, 1024, 0, stream>>>(pts, hist);
    scan_kernel<<<1, 256, 0, stream>>>(hist, cursor);
    scatter_kernel<<<256, 1024, 0, stream>>>(pts, cursor, psort);

    dim3 gg(32768, 3);
    gather_kernel<<<gg, 256, 0, stream>>>((const ushort*)feat, psort, out);
}